// Round 5
// baseline (15627.029 us; speedup 1.0000x reference)
//
#include <hip/hip_runtime.h>
#include <math.h>

#define NT   64
#define NB   16
#define INS  256
#define OUTS 256
#define WL   128
#define NC   256
#define NR   4
#define HIDN 512
#define G4   2048
#define WCH  391
#define COUT 927
#define EPSF 1e-6f
#define NBLK 64
#define THR  512

__device__ __forceinline__ float sigf(float x){ return 1.0f/(1.0f+expf(-x)); }
__device__ __forceinline__ float oneplusf(float x){ return fmaxf(x,0.0f)+log1pf(expf(-fabsf(x)))+1.0f; }

__device__ __forceinline__ float waveSum(float v){
#pragma unroll
  for(int o=32;o>0;o>>=1) v += __shfl_down(v,o,64);
  return v;
}
__device__ __forceinline__ float waveMax(float v){
#pragma unroll
  for(int o=32;o>0;o>>=1) v = fmaxf(v,__shfl_down(v,o,64));
  return v;
}

// relaxed agent-scope (LLC) accessors for cross-block data
__device__ __forceinline__ void g_storef(float* p, float v){
  __hip_atomic_store(p, v, __ATOMIC_RELAXED, __HIP_MEMORY_SCOPE_AGENT);
}
__device__ __forceinline__ float g_loadf(const float* p){
  return __hip_atomic_load((float*)p, __ATOMIC_RELAXED, __HIP_MEMORY_SCOPE_AGENT);
}
__device__ __forceinline__ float2 g_loadf2(const float* p){
  unsigned long long v = __hip_atomic_load((const unsigned long long*)p, __ATOMIC_RELAXED, __HIP_MEMORY_SCOPE_AGENT);
  union{unsigned long long u; float2 f;} c; c.u=v; return c.f;
}

// fence-free grid barrier (validated R2/R3): counter + flag, all NBLK co-resident
__device__ __forceinline__ void gridbar(int* bar, int* flag, int phase){
  __syncthreads();
  if (threadIdx.x == 0){
    asm volatile("s_waitcnt vmcnt(0) lgkmcnt(0)" ::: "memory");
    int prev = __hip_atomic_fetch_add(bar, 1, __ATOMIC_RELAXED, __HIP_MEMORY_SCOPE_AGENT);
    if (prev == NBLK*phase - 1){
      __hip_atomic_store(flag, phase, __ATOMIC_RELAXED, __HIP_MEMORY_SCOPE_AGENT);
    } else {
      while (__hip_atomic_load(flag, __ATOMIC_RELAXED, __HIP_MEMORY_SCOPE_AGENT) < phase)
        __builtin_amdgcn_s_sleep(1);
    }
    asm volatile("" ::: "memory");
  }
  __syncthreads();
}

// 512 threads carry 256 values duplicated 2x (v = row[tid&255])
__device__ float redDup(float v, bool isMax, float* s_tmp8){
  int lane=threadIdx.x&63, w=threadIdx.x>>6;
  v = isMax ? waveMax(v) : waveSum(v);
  if(lane==0) s_tmp8[w]=v;
  __syncthreads();
  float r;
  if(isMax){ r=s_tmp8[0]; for(int i=1;i<8;i++) r=fmaxf(r,s_tmp8[i]); }
  else     { r=0.f; for(int i=0;i<8;i++) r+=s_tmp8[i]; r*=0.5f; }
  __syncthreads();
  return r;
}
// 4 rows of 256; waves 0..3 rows, 4..7 duplicate. out4 = s_scal[0..3], tmp = s_scal[8..15]
__device__ void red4d(const float* v4x256, bool isMax, float* out4, float* tmp8){
  int lane=threadIdx.x&63, w=threadIdx.x>>6, row=w&3;
  const float* r=v4x256+row*256;
  float a=r[lane],b=r[lane+64],c=r[lane+128],d=r[lane+192];
  float x = isMax? fmaxf(fmaxf(a,b),fmaxf(c,d)) : (a+b+c+d);
  x = isMax? waveMax(x) : waveSum(x);
  if(lane==0) tmp8[w]=x;
  __syncthreads();
  if(threadIdx.x<4) out4[threadIdx.x]=tmp8[threadIdx.x];
  __syncthreads();
}

__global__ void k_zero(float* p, size_t n){
  size_t i = (size_t)blockIdx.x*blockDim.x + threadIdx.x;
  size_t st = (size_t)gridDim.x*blockDim.x;
  for(; i<n; i+=st) p[i]=0.0f;
}

// xpart[(t*NB+bi)][2048] = x_t @ Wx[0:256,:]
__global__ __launch_bounds__(256) void k_xpart(
    const float* __restrict__ in_data, const float* __restrict__ Wx, float* __restrict__ xpart)
{
  int jb = blockIdx.x & 15, rt = blockIdx.x >> 4;
  int jg = threadIdx.x & 15, rl = threadIdx.x >> 4;
  int row = rt*16 + rl;
  int j0 = jb*128 + jg*8;
  const float* x = in_data + (size_t)row*INS;
  float acc[8];
#pragma unroll
  for(int i=0;i<8;i++) acc[i]=0.0f;
  for(int k=0;k<INS;k++){
    float a = x[k];
    const float* w = Wx + (size_t)k*G4 + j0;
    float4 w0 = *(const float4*)w, w1 = *(const float4*)(w+4);
    acc[0]+=a*w0.x; acc[1]+=a*w0.y; acc[2]+=a*w0.z; acc[3]+=a*w0.w;
    acc[4]+=a*w1.x; acc[5]+=a*w1.y; acc[6]+=a*w1.z; acc[7]+=a*w1.w;
  }
  float* xp = xpart + (size_t)row*G4 + j0;
#pragma unroll
  for(int i=0;i<8;i++) xp[i]=acc[i];
}

// act float4 slot index with skew
#define ACT4(k4,bi) ((k4)*17 + (bi) + 2*((k4)>>6))

// LDS float offsets
#define O_BIG    0       // 17440 (act4 region / phase-E exp scratch)
#define O_GRED   17440   // 2560
#define O_CTRL   20000   // 928
#define O_PRD    20928   // 1024
#define O_PSI    21952   // 256
#define O_U2     22208   // 256
#define O_ALLOC  22464   // 256
#define O_WD     22720   // 256
#define O_SU     22976   // 256
#define O_SHIFT  23232   // 256
#define O_RK     23488   // 256
#define O_ER     23744   // 128
#define O_BWD    23872   // 1024
#define O_FWD    24896   // 1024
#define O_MN     25920   // 64
#define O_PRE    25984   // 64
#define O_SCAL   26048   // 32
#define O_WT     26080   // 8320 (weight tile: 2080 float4)
#define SH_FLOATS 34400  // 137.6 KB

__global__ __launch_bounds__(THR,1) void k_persist(
    const float* __restrict__ Wx, const float* __restrict__ Wh, const float* __restrict__ b_lstm,
    const float* __restrict__ Wc, const float* __restrict__ bc,
    const float* __restrict__ Wo, const float* __restrict__ bo,
    const float* __restrict__ Wr, const float* __restrict__ br,
    const float* __restrict__ xpart,
    float* mem_g, float* linkT_g, float* usages_g, float* prec_g,
    float* wdist_g, float* rdist_g, float* rdp_g, float* h_g, float* c_g,
    float* ctrl_g, float* dots_g, float* bwd_g, float* fwdp_g, float* rlog_g,
    float* out_g, int* bar)
{
  extern __shared__ float SH[];
  const int tid = threadIdx.x, blk = blockIdx.x;
  const int b = blk>>2, s = blk&3;
  float* s_big  = SH + O_BIG;
  float* s_gred = SH + O_GRED;
  float* s_ctrl = SH + O_CTRL;
  float* s_prd  = SH + O_PRD;
  float* s_psi  = SH + O_PSI;
  float* s_u2   = SH + O_U2;
  float* s_alloc= SH + O_ALLOC;
  float* s_wd   = SH + O_WD;
  float* s_su   = SH + O_SU;
  float* s_shift= SH + O_SHIFT;
  float* s_rk   = SH + O_RK;
  float* s_er   = SH + O_ER;
  float* s_bwd  = SH + O_BWD;
  float* s_fwd  = SH + O_FWD;
  float* s_mn   = SH + O_MN;
  float* s_pre  = SH + O_PRE;
  float* s_scal = SH + O_SCAL;
  float* s_wt   = SH + O_WT;
  float4* s_wt4 = (float4*)s_wt;
  int* flag = bar + 1;
  float4* act4 = (float4*)s_big;

  int bcount = 0;
  for(int t=0;t<=NT;t++){
    // ================= PHASE A =================
    // stage rdata(t-1) = sum of 4 partials -> act rows k4<128; h(t-1) -> 128..255
    for(int i=tid;i<2048;i+=THR){
      int bi=i>>7, k4=i&127;
      float4 a = {0,0,0,0};
#pragma unroll
      for(int p=0;p<4;p++){
        const float* q = rdp_g + bi*2048 + p*512 + 4*k4;
        float2 lo=g_loadf2(q), hi=g_loadf2(q+2);
        a.x+=lo.x; a.y+=lo.y; a.z+=hi.x; a.w+=hi.y;
      }
      act4[ACT4(k4,bi)] = a;
    }
    for(int i=tid;i<2048;i+=THR){
      int bi=i>>7, k4=i&127;
      const float* q = h_g + bi*512 + 4*k4;
      float2 lo=g_loadf2(q), hi=g_loadf2(q+2);
      float4 a = {lo.x,lo.y,hi.x,hi.y};
      act4[ACT4(128+k4,bi)] = a;
    }
    __syncthreads();
    // gates GEMM, LDS-tiled weights (4 tiles of 256 k)
    if(t<NT){
      int bi=tid&15, kq=(tid>>4)&3, cg=tid>>6;
      float a0=0,a1=0,a2=0,a3=0;
      for(int tt=0;tt<4;tt++){
        for(int idx=tid; idx<8192; idx+=THR){
          int kk=idx>>5, c=idx&31;
          int kg = tt*256+kk;
          int col = (c>>3)*512 + blk*8 + (c&7);
          float w = (kg<512) ? Wx[(size_t)(256+kg)*G4 + col]
                             : Wh[(size_t)(kg-512)*G4 + col];
          int f=kk>>2, q=f>>4, i=f&15;
          s_wt[(c*65 + i*4 + q)*4 + (kk&3)] = w;
        }
        __syncthreads();
        for(int i=0;i<16;i++){
          int k4g = tt*64 + kq*16 + i;
          float4 a = act4[ACT4(k4g,bi)];
          float4 w0 = s_wt4[(cg*4+0)*65 + i*4+kq];
          float4 w1 = s_wt4[(cg*4+1)*65 + i*4+kq];
          float4 w2 = s_wt4[(cg*4+2)*65 + i*4+kq];
          float4 w3 = s_wt4[(cg*4+3)*65 + i*4+kq];
          a0 += a.x*w0.x+a.y*w0.y+a.z*w0.z+a.w*w0.w;
          a1 += a.x*w1.x+a.y*w1.y+a.z*w1.z+a.w*w1.w;
          a2 += a.x*w2.x+a.y*w2.y+a.z*w2.z+a.w*w2.w;
          a3 += a.x*w3.x+a.y*w3.y+a.z*w3.z+a.w*w3.w;
        }
        __syncthreads();
      }
      int c0 = cg*4;
      s_gred[((c0+0)*4+kq)*16+bi]=a0;
      s_gred[((c0+1)*4+kq)*16+bi]=a1;
      s_gred[((c0+2)*4+kq)*16+bi]=a2;
      s_gred[((c0+3)*4+kq)*16+bi]=a3;
    }
    // out(t-1), LDS-tiled Wr/Wo (4 owned cols, K=1024)
    if(t>0){
      for(int idx=tid; idx<4096; idx+=THR){
        int kk=idx>>2, jl=idx&3;
        int j = blk*4+jl;
        float w = (kk<512) ? Wr[(size_t)kk*OUTS + j] : Wo[(size_t)(kk-512)*OUTS + j];
        int f=kk>>2, q=f>>5, i=f&31;
        s_wt[(jl*257 + i*8 + q)*4 + (kk&3)] = w;
      }
      __syncthreads();
      int bi=tid&15, kq8=(tid>>4)&7, jl=tid>>7;
      float acc=0;
      for(int i=0;i<32;i++){
        int f = kq8*32 + i;
        float4 a = act4[ACT4(f,bi)];
        float4 w = s_wt4[jl*257 + i*8 + kq8];
        acc += a.x*w.x+a.y*w.y+a.z*w.z+a.w*w.w;
      }
      s_gred[2048 + (jl*8+kq8)*16+bi] = acc;
    }
    __syncthreads();
    // LSTM for owned 8 jj
    if(t<NT && tid<128){
      int bi=tid&15, jl=tid>>4;
      float g[4];
#pragma unroll
      for(int gg=0;gg<4;gg++){
        int c = gg*8+jl;
        float v = s_gred[(c*4+0)*16+bi]+s_gred[(c*4+1)*16+bi]+s_gred[(c*4+2)*16+bi]+s_gred[(c*4+3)*16+bi];
        int col = gg*512 + blk*8 + jl;
        v += xpart[((size_t)t*NB+bi)*G4 + col] + b_lstm[col];
        g[gg]=v;
      }
      int ci = bi*HIDN + blk*8 + jl;
      float c = sigf(g[1])*c_g[ci] + sigf(g[0])*tanhf(g[2]);
      float h = sigf(g[3])*tanhf(c);
      c_g[ci]=c;
      g_storef(h_g+ci, h);
    }
    if(t>0 && tid>=128 && tid<192){
      int r2=tid-128, bi=r2&15, jl=r2>>4;
      int j = blk*4+jl;
      float acc = bo[j]+br[j];
#pragma unroll
      for(int q=0;q<8;q++) acc += s_gred[2048+(jl*8+q)*16+bi];
      out_g[((size_t)(t-1)*NB+bi)*OUTS + j] = acc;
    }
    if(t==NT) break;
    gridbar(bar,flag,++bcount);

    // ================= PHASE B: ctrl =================
    for(int i=tid;i<2048;i+=THR){
      int bi=i>>7, k4=i&127;
      const float* q = h_g + bi*512 + 4*k4;
      float2 lo=g_loadf2(q), hi=g_loadf2(q+2);
      float4 a = {lo.x,lo.y,hi.x,hi.y};
      act4[ACT4(k4,bi)] = a;
    }
    // Wc tile: 15 owned cols (+1 pad), K=512
    for(int idx=tid; idx<8192; idx+=THR){
      int kk=idx>>4, cl=idx&15;
      int j = blk*15+cl;
      float w = (cl<15 && j<COUT) ? Wc[(size_t)kk*COUT + j] : 0.f;
      int f=kk>>2, q=f>>6, i=f&63;
      s_wt[(cl*129 + i*2 + q)*4 + (kk&3)] = w;
    }
    __syncthreads();
    {
      int bi=tid&15, kq=(tid>>4)&1, cl=tid>>5;
      float acc=0;
      for(int i=0;i<64;i++){
        int f = kq*64+i;
        float4 a = act4[ACT4(f,bi)];
        float4 w = s_wt4[cl*129 + i*2 + kq];
        acc += a.x*w.x+a.y*w.y+a.z*w.z+a.w*w.w;
      }
      s_gred[(cl*2+kq)*16+bi]=acc;
    }
    __syncthreads();
    if(tid<256){
      int bi=tid&15, cl=tid>>4;
      int j = blk*15+cl;
      if(cl<15 && j<COUT){
        float a = bc[j] + s_gred[(cl*2+0)*16+bi] + s_gred[(cl*2+1)*16+bi];
        g_storef(ctrl_g + bi*928 + j, fminf(fmaxf(a,-20.f),20.f));
      }
    }
    gridbar(bar,flag,++bcount);

    // ================= PHASE C =================
    for(int i=tid;i<464;i+=THR){
      float2 v = g_loadf2(ctrl_g + b*928 + 2*i);
      s_ctrl[2*i]=v.x; s_ctrl[2*i+1]=v.y;
    }
    for(int i=tid;i<512;i+=THR){
      float2 v = g_loadf2(rdist_g + b*1024 + 2*i);
      s_prd[2*i]=v.x; s_prd[2*i+1]=v.y;
    }
    __syncthreads();
    if(tid<256){
      int n=tid;
      float psi=1.f;
#pragma unroll
      for(int r=0;r<NR;r++) psi *= 1.f - sigf(s_ctrl[384+r])*s_prd[r*NC+n];
      s_psi[n]=psi;
      float uold = g_loadf(usages_g + b*NC+n);
      float wprev= g_loadf(wdist_g + b*NC+n);
      float u = (uold + wprev - uold*wprev)*psi;
      if((n>>6)==s) g_storef(usages_g + b*NC+n, u);
      s_u2[n] = u*(1.f-EPSF)+EPSF;
    } else if(tid<384){
      int w=tid-256; s_er[w]=sigf(s_ctrl[WL+w]);
    } else if(tid>=448){
      int l=tid-448;
      float v = s_ctrl[l]*s_ctrl[l] + s_ctrl[l+64]*s_ctrl[l+64];
      v = waveSum(v);
      if(l==0) s_scal[0]=v;      // write-key norm^2
    }
    __syncthreads();
    // stable rank (matches stable argsort)
    {
      int n=tid&255, half=tid>>8;
      float u2=s_u2[n]; int cnt=0;
      for(int jj=0;jj<128;jj++){
        int j=half*128+jj; float uj=s_u2[j];
        cnt += (uj<u2)||(uj==u2 && j<n);
      }
      s_gred[half*256+n]=(float)cnt;
    }
    __syncthreads();
    if(tid<256){
      int rk=(int)(s_gred[tid]+s_gred[256+tid]);
      s_rk[tid]=(float)rk;
      s_su[rk]=s_u2[tid];
    }
    __syncthreads();
    if(tid==0){
      float run=1.f;
      for(int i=0;i<NC;i++){ s_shift[i]=run; run*=s_su[i]; }
    }
    __syncthreads();
    if(tid<256){ int rk=(int)s_rk[tid]; s_alloc[tid]=(1.f-s_su[rk])*s_shift[rk]; }
    // write-key dots for owned rows (old mem)
    {
      int nr=tid>>3, wq=tid&7; int n=s*64+nr;
      const float4* mr = (const float4*)(mem_g + ((size_t)(b*NC+n))*WL) + wq*4;
      float dt=0,m2=0;
#pragma unroll
      for(int w4=0;w4<4;w4++){
        float4 m=mr[w4]; int w=wq*16+4*w4;
        dt += m.x*s_ctrl[w]+m.y*s_ctrl[w+1]+m.z*s_ctrl[w+2]+m.w*s_ctrl[w+3];
        m2 += m.x*m.x+m.y*m.y+m.z*m.z+m.w*m.w;
      }
      s_gred[tid]=dt; s_gred[512+tid]=m2;
    }
    __syncthreads();
    if(tid<64){
      float dt=0,m2=0;
#pragma unroll
      for(int q=0;q<8;q++){ dt+=s_gred[tid*8+q]; m2+=s_gred[512+tid*8+q]; }
      float w_beta=oneplusf(s_ctrl[388]);
      float lg = dt*w_beta/(sqrtf(s_scal[0])*sqrtf(m2)+EPSF);
      g_storef(dots_g + b*NC + s*64+tid, lg);
    }
    gridbar(bar,flag,++bcount);

    // ================= PHASE D =================
    for(int i=tid;i<128;i+=THR){
      float2 v=g_loadf2(dots_g + b*NC + 2*i);
      s_gred[2*i]=v.x; s_gred[2*i+1]=v.y;
    }
    __syncthreads();
    float v = s_gred[tid&255];
    float mx = redDup(v,true,s_scal);
    float e = expf(v-mx);
    float se = redDup(e,false,s_scal);
    if(tid<256){
      float cw = e/se;
      float ag=sigf(s_ctrl[389]), wg=sigf(s_ctrl[390]);
      float wd = wg*(ag*s_alloc[tid]+(1.f-ag)*cw);
      s_wd[tid]=wd;
      if((tid>>6)==s) g_storef(wdist_g+b*NC+tid, wd);
    }
    __syncthreads();
    float swd = redDup(s_wd[tid&255],false,s_scal);
    if(tid<64){
      int n=s*64+tid;
      float po = prec_g[b*NC+n];          // owner-only
      s_pre[tid]=po;
      prec_g[b*NC+n] = (1.f-swd)*po + s_wd[n];
    }
    __syncthreads();
    // linkT update (owned cols) + bwd partials
    {
      int nr=tid>>3, ic=tid&7; int n=s*64+nr;
      float wdn=s_wd[n], pren=s_pre[nr];
      float bw0=0,bw1=0,bw2=0,bw3=0;
      float4* lp=(float4*)(linkT_g + ((size_t)(b*NC+n))*NC + ic*32);
#pragma unroll 2
      for(int q4=0;q4<8;q4++){
        float4 l=lp[q4];
        int i0=ic*32+4*q4;
        float w0=s_wd[i0],w1=s_wd[i0+1],w2=s_wd[i0+2],w3=s_wd[i0+3];
        float l0=(i0  ==n)?0.f:((1.f-w0-wdn)*l.x+w0*pren);
        float l1=(i0+1==n)?0.f:((1.f-w1-wdn)*l.y+w1*pren);
        float l2=(i0+2==n)?0.f:((1.f-w2-wdn)*l.z+w2*pren);
        float l3=(i0+3==n)?0.f:((1.f-w3-wdn)*l.w+w3*pren);
        lp[q4]=make_float4(l0,l1,l2,l3);
        bw0+=l0*s_prd[0*NC+i0]+l1*s_prd[0*NC+i0+1]+l2*s_prd[0*NC+i0+2]+l3*s_prd[0*NC+i0+3];
        bw1+=l0*s_prd[1*NC+i0]+l1*s_prd[1*NC+i0+1]+l2*s_prd[1*NC+i0+2]+l3*s_prd[1*NC+i0+3];
        bw2+=l0*s_prd[2*NC+i0]+l1*s_prd[2*NC+i0+1]+l2*s_prd[2*NC+i0+2]+l3*s_prd[2*NC+i0+3];
        bw3+=l0*s_prd[3*NC+i0]+l1*s_prd[3*NC+i0+1]+l2*s_prd[3*NC+i0+2]+l3*s_prd[3*NC+i0+3];
      }
      s_gred[(0*64+nr)*8+ic]=bw0; s_gred[(1*64+nr)*8+ic]=bw1;
      s_gred[(2*64+nr)*8+ic]=bw2; s_gred[(3*64+nr)*8+ic]=bw3;
    }
    __syncthreads();
    if(tid<256){
      int r=tid>>6, nr=tid&63;
      float bwv=0;
#pragma unroll
      for(int q=0;q<8;q++) bwv+=s_gred[(r*64+nr)*8+q];
      g_storef(bwd_g + b*1024 + r*NC + s*64+nr, bwv);
    }
    // fwd partials over owned cols, all rows i
    {
      int i=tid&255, dh=tid>>8;
      float f0=0,f1=0;
      const float* lp = linkT_g + ((size_t)(b*NC+s*64))*NC + i;
      for(int nn=0;nn<64;nn++){
        float l = lp[(size_t)nn*NC];
        f0 += l*s_prd[(2*dh  )*NC + s*64+nn];
        f1 += l*s_prd[(2*dh+1)*NC + s*64+nn];
      }
      g_storef(fwdp_g + b*4096 + s*1024 + (2*dh  )*NC + i, f0);
      g_storef(fwdp_g + b*4096 + s*1024 + (2*dh+1)*NC + i, f1);
    }
    // mem update (owned rows)
    {
      int nr=tid>>3, wq=tid&7; int n=s*64+nr;
      float ps=s_psi[n], wdn=s_wd[n];
      float4* mr=(float4*)(mem_g + ((size_t)(b*NC+n))*WL) + wq*4;
#pragma unroll
      for(int w4=0;w4<4;w4++){
        float4 m=mr[w4]; int w=wq*16+4*w4;
        m.x=m.x*ps*(1.f-wdn*s_er[w  ])+wdn*s_ctrl[256+w  ];
        m.y=m.y*ps*(1.f-wdn*s_er[w+1])+wdn*s_ctrl[256+w+1];
        m.z=m.z*ps*(1.f-wdn*s_er[w+2])+wdn*s_ctrl[256+w+2];
        m.w=m.w*ps*(1.f-wdn*s_er[w+3])+wdn*s_ctrl[256+w+3];
        mr[w4]=m;
      }
    }
    __syncthreads();
    // read dots + new norms (owned rows)
    {
      int nr=tid>>3, wq=tid&7; int n=s*64+nr;
      const float4* mr=(const float4*)(mem_g + ((size_t)(b*NC+n))*WL) + wq*4;
      const float* k0=s_ctrl+WCH+0*132;
      const float* k1=s_ctrl+WCH+1*132;
      const float* k2=s_ctrl+WCH+2*132;
      const float* k3=s_ctrl+WCH+3*132;
      float d0=0,d1=0,d2=0,d3=0,m2=0;
#pragma unroll
      for(int w4=0;w4<4;w4++){
        float4 m=mr[w4]; int w=wq*16+4*w4;
        d0+=m.x*k0[w]+m.y*k0[w+1]+m.z*k0[w+2]+m.w*k0[w+3];
        d1+=m.x*k1[w]+m.y*k1[w+1]+m.z*k1[w+2]+m.w*k1[w+3];
        d2+=m.x*k2[w]+m.y*k2[w+1]+m.z*k2[w+2]+m.w*k2[w+3];
        d3+=m.x*k3[w]+m.y*k3[w+1]+m.z*k3[w+2]+m.w*k3[w+3];
        m2+=m.x*m.x+m.y*m.y+m.z*m.z+m.w*m.w;
      }
      s_gred[(0*64+nr)*8+wq]=d0; s_gred[(1*64+nr)*8+wq]=d1;
      s_gred[(2*64+nr)*8+wq]=d2; s_gred[(3*64+nr)*8+wq]=d3;
      s_gred[2048+tid]=m2;
    }
    __syncthreads();
    if(tid<64){
      float m2=0;
#pragma unroll
      for(int q=0;q<8;q++) m2+=s_gred[2048+tid*8+q];
      s_mn[tid]=sqrtf(m2);
    }
    if(tid<256){
      int r=tid>>6, l=tid&63;
      const float* kk=s_ctrl+WCH+r*132;
      float kv = kk[l]*kk[l]+kk[l+64]*kk[l+64];
      kv = waveSum(kv);
      if(l==0) s_scal[4+r]=kv;
    }
    __syncthreads();
    if(tid<256){
      int r=tid>>6, nr=tid&63;
      float dt=0;
#pragma unroll
      for(int q=0;q<8;q++) dt+=s_gred[(r*64+nr)*8+q];
      float rb=oneplusf(s_ctrl[WCH+r*132+128]);
      float lg = dt*rb/(sqrtf(s_scal[4+r])*s_mn[nr]+EPSF);
      g_storef(rlog_g + b*1024 + r*NC + s*64+nr, lg);
    }
    gridbar(bar,flag,++bcount);

    // ================= PHASE E =================
    for(int i=tid;i<512;i+=THR){           // fwd = sum of 4 partials
      float2 a={0,0};
#pragma unroll
      for(int p=0;p<4;p++){
        float2 vv=g_loadf2(fwdp_g + b*4096 + p*1024 + 2*i);
        a.x+=vv.x; a.y+=vv.y;
      }
      s_fwd[2*i]=a.x; s_fwd[2*i+1]=a.y;
    }
    for(int i=tid;i<512;i+=THR){
      float2 vv=g_loadf2(bwd_g + b*1024 + 2*i);
      s_bwd[2*i]=vv.x; s_bwd[2*i+1]=vv.y;
    }
    for(int i=tid;i<512;i+=THR){
      float2 vv=g_loadf2(rlog_g + b*1024 + 2*i);
      s_big[2*i]=vv.x; s_big[2*i+1]=vv.y;
    }
    __syncthreads();
    // sharpen: wave w -> row (0-3 fwd, 4-7 bwd)
    {
      int l=tid&63, w=tid>>6;
      float* rowp = (w<4)? (s_fwd + w*NC) : (s_bwd + (w-4)*NC);
      float a=rowp[l]+EPSF, b2=rowp[l+64]+EPSF, c2=rowp[l+128]+EPSF, d2=rowp[l+192]+EPSF;
      float mxr = waveMax(fmaxf(fmaxf(a,b2),fmaxf(c2,d2)));
      if(l==0) s_scal[16+w]=mxr;
      __syncthreads();
      mxr = s_scal[16+w];
      float ff = oneplusf(s_ctrl[919+w]);
      a=powf(a/mxr,ff); b2=powf(b2/mxr,ff); c2=powf(c2/mxr,ff); d2=powf(d2/mxr,ff);
      float sm = waveSum(a+b2+c2+d2);
      if(l==0) s_scal[24+w]=sm;
      rowp[l]=a; rowp[l+64]=b2; rowp[l+128]=c2; rowp[l+192]=d2;
    }
    __syncthreads();
    // read softmax
    red4d(s_big,true,s_scal,s_scal+8);
    if(tid<256){
#pragma unroll
      for(int r=0;r<NR;r++) s_big[r*NC+tid]=expf(s_big[r*NC+tid]-s_scal[r]);
    }
    __syncthreads();
    red4d(s_big,false,s_scal,s_scal+8);
    if(tid<256){
      int n=tid;
#pragma unroll
      for(int r=0;r<NR;r++){
        float cr = s_big[r*NC+n]/s_scal[r];
        float fwdn = s_fwd[r*NC+n]/s_scal[24+r];
        float bwdn = s_bwd[r*NC+n]/s_scal[28+r];
        int mo = WCH+r*132+129;
        float m0=s_ctrl[mo],m1=s_ctrl[mo+1],m2s=s_ctrl[mo+2];
        float mm=fmaxf(m0,fmaxf(m1,m2s));
        float e0=expf(m0-mm),e1=expf(m1-mm),e2=expf(m2s-mm);
        float es=e0+e1+e2;
        float rdv=(e0*bwdn+e1*cr+e2*fwdn)/es;
        s_prd[r*NC+n]=rdv;
        if((n>>6)==s) g_storef(rdist_g + b*1024 + r*NC + n, rdv);
      }
    }
    __syncthreads();
    // rdata partials over owned rows
    {
      int w=tid&127, nq=tid>>7;
      float a0=0,a1=0,a2=0,a3=0;
      for(int nn=0;nn<16;nn++){
        int n=s*64+nq*16+nn;
        float mv = mem_g[((size_t)(b*NC+n))*WL + w];
        a0+=s_prd[0*NC+n]*mv; a1+=s_prd[1*NC+n]*mv;
        a2+=s_prd[2*NC+n]*mv; a3+=s_prd[3*NC+n]*mv;
      }
      s_gred[(0*4+nq)*128+w]=a0; s_gred[(1*4+nq)*128+w]=a1;
      s_gred[(2*4+nq)*128+w]=a2; s_gred[(3*4+nq)*128+w]=a3;
    }
    __syncthreads();
    {
      int r=tid>>7, w=tid&127;
      float rd = s_gred[(r*4+0)*128+w]+s_gred[(r*4+1)*128+w]+s_gred[(r*4+2)*128+w]+s_gred[(r*4+3)*128+w];
      g_storef(rdp_g + b*2048 + s*512 + r*128 + w, rd);
    }
    gridbar(bar,flag,++bcount);
  }
}

extern "C" void kernel_launch(void* const* d_in, const int* in_sizes, int n_in,
                              void* d_out, int out_size, void* d_ws, size_t ws_size,
                              hipStream_t stream) {
  const float* in_data = (const float*)d_in[0];
  const float* Wx      = (const float*)d_in[1];
  const float* Wh      = (const float*)d_in[2];
  const float* b_lstm  = (const float*)d_in[3];
  const float* Wc      = (const float*)d_in[4];
  const float* bc      = (const float*)d_in[5];
  const float* Wo      = (const float*)d_in[6];
  const float* bo      = (const float*)d_in[7];
  const float* Wr      = (const float*)d_in[8];
  const float* br      = (const float*)d_in[9];
  float* out = (float*)d_out;
  float* ws  = (float*)d_ws;

  size_t off=0;
  float* mem_    = ws+off; off += (size_t)NB*NC*WL;     // 524288
  float* linkT_  = ws+off; off += (size_t)NB*NC*NC;     // 1048576
  float* usages_ = ws+off; off += NB*NC;
  float* prec_   = ws+off; off += NB*NC;
  float* wdist_  = ws+off; off += NB*NC;
  float* rdist_  = ws+off; off += NB*NR*NC;             // 16384
  float* rdp_    = ws+off; off += (size_t)NB*4*NR*WL;   // 32768
  float* h_      = ws+off; off += NB*HIDN;
  float* c_      = ws+off; off += NB*HIDN;
  int*   bar_    = (int*)(ws+off); off += 16;
  size_t zero_floats = off;                             // ~1.65M
  float* ctrl_   = ws+off; off += NB*928;
  float* dots_   = ws+off; off += NB*NC;
  float* bwd_    = ws+off; off += NB*NR*NC;
  float* fwdp_   = ws+off; off += (size_t)NB*4*NR*NC;   // 65536
  float* rlog_   = ws+off; off += NB*NR*NC;
  float* xpart_  = ws+off; off += (size_t)NT*NB*G4;     // 2097152
  // total ~3.87M floats = 15.5 MB (< R2's proven 17.2 MB)

  static const size_t SH_BYTES = SH_FLOATS*sizeof(float);
  hipFuncSetAttribute((const void*)k_persist,
                      hipFuncAttributeMaxDynamicSharedMemorySize, (int)SH_BYTES);

  k_zero<<<256,256,0,stream>>>(ws, zero_floats);
  k_xpart<<<1024,256,0,stream>>>(in_data, Wx, xpart_);

  k_persist<<<NBLK,THR,SH_BYTES,stream>>>(Wx,Wh,b_lstm,Wc,bc,Wo,bo,Wr,br,
                                          xpart_,mem_,linkT_,usages_,prec_,
                                          wdist_,rdist_,rdp_,h_,c_,
                                          ctrl_,dots_,bwd_,fwdp_,rlog_,out,bar_);
}

// Round 8
// 5850.535 us; speedup vs baseline: 2.6710x; 2.6710x over previous
//
#include <hip/hip_runtime.h>
#include <math.h>

#define NT   64
#define NB   16
#define OUTS 256
#define WL   128
#define NC   256
#define NR   4
#define HIDN 512
#define G4   2048
#define WCH  391
#define COUT 927
#define EPSF 1e-6f
#define NBLK 256
#define THR  512
#define NSB  16    // blocks per batch
#define SLC  16    // cells owned per block

__device__ __forceinline__ float sigf(float x){ return 1.0f/(1.0f+expf(-x)); }
__device__ __forceinline__ float oneplusf(float x){ return fmaxf(x,0.0f)+log1pf(expf(-fabsf(x)))+1.0f; }

__device__ __forceinline__ float waveSum(float v){
#pragma unroll
  for(int o=32;o>0;o>>=1) v += __shfl_down(v,o,64);
  return v;
}
__device__ __forceinline__ float waveMax(float v){
#pragma unroll
  for(int o=32;o>0;o>>=1) v = fmaxf(v,__shfl_down(v,o,64));
  return v;
}

// relaxed agent-scope (LLC-coherent) accessors for cross-block tensors
__device__ __forceinline__ void g_storef(float* p, float v){
  __hip_atomic_store(p, v, __ATOMIC_RELAXED, __HIP_MEMORY_SCOPE_AGENT);
}
__device__ __forceinline__ float g_loadf(const float* p){
  return __hip_atomic_load((float*)p, __ATOMIC_RELAXED, __HIP_MEMORY_SCOPE_AGENT);
}
__device__ __forceinline__ float2 g_loadf2(const float* p){
  unsigned long long v = __hip_atomic_load((const unsigned long long*)p, __ATOMIC_RELAXED, __HIP_MEMORY_SCOPE_AGENT);
  union{unsigned long long u; float2 f;} c; c.u=v; return c.f;
}

// per-batch barrier (16 blocks), fence-free protocol validated R3/R5
__device__ __forceinline__ void batbar(int* cnt, int* flg, int phase){
  __syncthreads();
  if (threadIdx.x == 0){
    asm volatile("s_waitcnt vmcnt(0) lgkmcnt(0)" ::: "memory");
    int prev = __hip_atomic_fetch_add(cnt, 1, __ATOMIC_RELAXED, __HIP_MEMORY_SCOPE_AGENT);
    if (prev == NSB*phase - 1){
      __hip_atomic_store(flg, phase, __ATOMIC_RELAXED, __HIP_MEMORY_SCOPE_AGENT);
    } else {
      while (__hip_atomic_load(flg, __ATOMIC_RELAXED, __HIP_MEMORY_SCOPE_AGENT) < phase)
        __builtin_amdgcn_s_sleep(1);
    }
    asm volatile("" ::: "memory");
  }
  __syncthreads();
}

__global__ void k_zero(float* p, size_t n){
  size_t i = (size_t)blockIdx.x*blockDim.x + threadIdx.x;
  size_t st = (size_t)gridDim.x*blockDim.x;
  for(; i<n; i+=st) p[i]=0.0f;
}

// xpart[(t*NB+bi)][2048] = x_t @ Wx[0:256,:]  (hoisted, fully parallel)
__global__ __launch_bounds__(256) void k_xpart(
    const float* __restrict__ in_data, const float* __restrict__ Wx, float* __restrict__ xpart)
{
  int jb = blockIdx.x & 15, rt = blockIdx.x >> 4;
  int jg = threadIdx.x & 15, rl = threadIdx.x >> 4;
  int row = rt*16 + rl;
  int j0 = jb*128 + jg*8;
  const float* x = in_data + (size_t)row*256;
  float acc[8];
#pragma unroll
  for(int i=0;i<8;i++) acc[i]=0.0f;
  for(int k=0;k<256;k++){
    float a = x[k];
    const float* w = Wx + (size_t)k*G4 + j0;
    float4 w0 = *(const float4*)w, w1 = *(const float4*)(w+4);
    acc[0]+=a*w0.x; acc[1]+=a*w0.y; acc[2]+=a*w0.z; acc[3]+=a*w0.w;
    acc[4]+=a*w1.x; acc[5]+=a*w1.y; acc[6]+=a*w1.z; acc[7]+=a*w1.w;
  }
  float* xp = xpart + (size_t)row*G4 + j0;
#pragma unroll
  for(int i=0;i<8;i++) xp[i]=acc[i];
}

__global__ __launch_bounds__(THR,1) void k_persist(
    const float* __restrict__ Wx, const float* __restrict__ Wh, const float* __restrict__ b_lstm,
    const float* __restrict__ Wc, const float* __restrict__ bc,
    const float* __restrict__ Wo, const float* __restrict__ bo,
    const float* __restrict__ Wr, const float* __restrict__ br,
    const float* __restrict__ xpart,
    float* mem_g, float* linkT_g, float* usages_g, float* prec_g,
    float* wdist_g, float* rdist_g, float* rdp_g, float* h_g, float* c_g,
    float* ctrl_g, float* dots_g, float* bwd_g, float* fwdp_g, float* rlog_g,
    float* out_g, int* bar)
{
  __shared__ float s_act[1024];
  __shared__ float s_ctrl[928];
  __shared__ float s_prd[1024];
  __shared__ float s_psi[256], s_u2[256], s_alloc[256], s_wd[256];
  __shared__ float s_er[128];
  __shared__ float s_preo[16], s_mn[16];
  __shared__ float s_scal[32], s_sct[16];
  __shared__ float s_rk[256], s_su[256], s_shift[256];
  __shared__ float s_link[SLC*256];   // owned linkT rows (new)
  __shared__ float s_mem[SLC*128];    // owned mem rows (new)
  __shared__ float s_red[2560];
  __shared__ float s_fwd[1024], s_bwd[1024];

  const int tid = threadIdx.x, blk = blockIdx.x;
  const int s = blk & 15, b = blk >> 4;
  int* cnt = bar + b*32;
  int* flg = bar + b*32 + 16;
  int bcnt = 0;

  for(int t=0;t<=NT;t++){
    // double-buffer parity: read old (t&1), write new ((t+1)&1)
    const float* h_old = h_g + (t&1)*(NB*HIDN);
    float*       h_new = h_g + ((t+1)&1)*(NB*HIDN);
    const float* u_old = usages_g + (t&1)*(NB*NC);
    float*       u_new = usages_g + ((t+1)&1)*(NB*NC);

    // ============ PHASE A: stage act, gates GEMM, LSTM, out(t-1) ============
    if(tid<256){
      float2 a={0,0};
#pragma unroll
      for(int p=0;p<NSB;p++){
        float2 v = g_loadf2(rdp_g + ((size_t)(b*NSB+p))*512 + 2*tid);
        a.x+=v.x; a.y+=v.y;
      }
      s_act[2*tid]=a.x; s_act[2*tid+1]=a.y;
    } else {
      int i=tid-256;
      float2 v = g_loadf2(h_old + b*HIDN + 2*i);
      s_act[512+2*i]=v.x; s_act[512+2*i+1]=v.y;
    }
    __syncthreads();
    if(t<NT){
      int jj=tid&31, ks=tid>>5;        // 32 jj x 16 ksplit(64)
      int col0 = s*32+jj;
      float a0=0,a1=0,a2=0,a3=0;
      for(int kk=0;kk<64;kk++){
        int k=ks*64+kk;
        float av=s_act[k];
        const float* wr = (k<512) ? (Wx + (size_t)(256+k)*G4) : (Wh + (size_t)(k-512)*G4);
        a0 += av*wr[col0];
        a1 += av*wr[512+col0];
        a2 += av*wr[1024+col0];
        a3 += av*wr[1536+col0];
      }
      s_red[(0*32+jj)*16+ks]=a0;
      s_red[(1*32+jj)*16+ks]=a1;
      s_red[(2*32+jj)*16+ks]=a2;
      s_red[(3*32+jj)*16+ks]=a3;
    }
    if(t>0){
      int jl=tid&15, ks2=tid>>4;       // 16 j x 32 ksplit(32)
      int j=s*16+jl;
      float acc=0;
      for(int kk=0;kk<32;kk++){
        int k=ks2*32+kk;
        float av=s_act[k];
        const float* wr=(k<512)?(Wr+(size_t)k*OUTS):(Wo+(size_t)(k-512)*OUTS);
        acc += av*wr[j];
      }
      s_red[2048 + jl*32+ks2]=acc;
    }
    __syncthreads();
    if(t<NT && tid<32){
      int jj=tid;
      float g[4];
#pragma unroll
      for(int gg=0;gg<4;gg++){
        float v=0;
#pragma unroll
        for(int q=0;q<16;q++) v+=s_red[(gg*32+jj)*16+q];
        int col=gg*512+s*32+jj;
        v += xpart[((size_t)t*NB+b)*G4 + col] + b_lstm[col];
        g[gg]=v;
      }
      int ci = b*HIDN + s*32+jj;
      float c = sigf(g[1])*c_g[ci] + sigf(g[0])*tanhf(g[2]);
      float h = sigf(g[3])*tanhf(c);
      c_g[ci]=c;
      g_storef(h_new+ci, h);
    }
    if(t>0 && tid>=64 && tid<80){
      int jl=tid-64; int j=s*16+jl;
      float acc=bo[j]+br[j];
#pragma unroll
      for(int q=0;q<32;q++) acc+=s_red[2048+jl*32+q];
      out_g[((size_t)(t-1)*NB+b)*OUTS + j]=acc;
    }
    if(t==NT) break;
    batbar(cnt,flg,++bcnt);

    // ============ PHASE B: ctrl = clip(h @ Wc + bc) ============
    if(tid<256){
      float2 v = g_loadf2(h_new + b*HIDN + 2*tid);
      s_act[2*tid]=v.x; s_act[2*tid+1]=v.y;
    }
    __syncthreads();
    {
      int cl=tid&63, ks=tid>>6;        // 64 col-slots x 8 ksplit(64)
      int j=s*58+cl;
      float acc=0;
      if(cl<58 && j<COUT){
        for(int kk=0;kk<64;kk++){
          int k=ks*64+kk;
          acc += s_act[k]*Wc[(size_t)k*COUT + j];
        }
      }
      s_red[cl*8+ks]=acc;
    }
    __syncthreads();
    if(tid<58){
      int j=s*58+tid;
      if(j<COUT){
        float a=bc[j];
#pragma unroll
        for(int q=0;q<8;q++) a+=s_red[tid*8+q];
        g_storef(ctrl_g + b*928 + j, fminf(fmaxf(a,-20.f),20.f));
      }
    }
    batbar(cnt,flg,++bcnt);

    // ============ PHASE C: psi/usage/alloc + write-key dots ============
    if(tid<464){
      float2 v = g_loadf2(ctrl_g + b*928 + 2*tid);
      s_ctrl[2*tid]=v.x; s_ctrl[2*tid+1]=v.y;
    }
    {
      float2 v = g_loadf2(rdist_g + b*1024 + 2*tid);
      s_prd[2*tid]=v.x; s_prd[2*tid+1]=v.y;
    }
    __syncthreads();
    if(tid<256){
      int n=tid;
      float psi=1.f;
#pragma unroll
      for(int r=0;r<NR;r++) psi *= 1.f - sigf(s_ctrl[384+r])*s_prd[r*256+n];
      s_psi[n]=psi;
      float uo=g_loadf(u_old+b*256+n), pw=g_loadf(wdist_g+b*256+n);
      float u=(uo+pw-uo*pw)*psi;
      if((n>>4)==s) g_storef(u_new+b*256+n,u);
      s_u2[n]=u*(1.f-EPSF)+EPSF;
    } else if(tid<384){
      int w=tid-256; s_er[w]=sigf(s_ctrl[128+w]);
    } else if(tid>=448){
      int l=tid-448;
      float v=s_ctrl[l]*s_ctrl[l]+s_ctrl[l+64]*s_ctrl[l+64];
      v=waveSum(v);
      if(l==0) s_scal[0]=v;
    }
    __syncthreads();
    {
      int n=tid&255, hf=tid>>8;
      float u2=s_u2[n]; int c=0;
      for(int jj=0;jj<128;jj++){
        int j=hf*128+jj; float uj=s_u2[j];
        c += (uj<u2)||(uj==u2 && j<n);
      }
      s_red[hf*256+n]=(float)c;
    }
    __syncthreads();
    if(tid<256){
      int rk=(int)(s_red[tid]+s_red[256+tid]);
      s_rk[tid]=(float)rk;
      s_su[rk]=s_u2[tid];
    }
    __syncthreads();
    if(tid<16){
      float run=1.f;
#pragma unroll
      for(int i=0;i<16;i++){ int idx=tid*16+i; s_shift[idx]=run; run*=s_su[idx]; }
      s_sct[tid]=run;
    }
    __syncthreads();
    if(tid==0){
      float run=1.f;
      for(int j=0;j<16;j++){ float t2=s_sct[j]; s_sct[j]=run; run*=t2; }
    }
    __syncthreads();
    if(tid<256){
      int rk=(int)s_rk[tid];
      s_alloc[tid]=(1.f-s_u2[tid])*s_shift[rk]*s_sct[rk>>4];
    }
    {
      int nr=tid>>5, wq=tid&31;        // 16 owned rows x 32 float4
      int n=s*16+nr;
      float4 m=((const float4*)(mem_g + ((size_t)(b*256+n))*WL))[wq];
      int w=wq*4;
      float dt=m.x*s_ctrl[w]+m.y*s_ctrl[w+1]+m.z*s_ctrl[w+2]+m.w*s_ctrl[w+3];
      float m2=m.x*m.x+m.y*m.y+m.z*m.z+m.w*m.w;
      s_red[nr*32+wq]=dt; s_red[512+nr*32+wq]=m2;
    }
    __syncthreads();
    if(tid<16){
      float dt=0,m2=0;
#pragma unroll
      for(int q=0;q<32;q++){ dt+=s_red[tid*32+q]; m2+=s_red[512+tid*32+q]; }
      float wb=oneplusf(s_ctrl[388]);
      float lg=dt*wb/(sqrtf(s_scal[0])*sqrtf(m2)+EPSF);
      g_storef(dots_g+b*256+s*16+tid, lg);
    }
    batbar(cnt,flg,++bcnt);

    // ============ PHASE D: write softmax, link, fwd/bwd, mem, read dots ============
    if(tid<128){
      float2 v=g_loadf2(dots_g+b*256+2*tid);
      s_red[2*tid]=v.x; s_red[2*tid+1]=v.y;
    }
    __syncthreads();
    {
      float lv=s_red[tid&255];
      float mv=waveMax(lv);
      if((tid&63)==0) s_scal[8+(tid>>6)]=mv;
      __syncthreads();
      float mx=s_scal[8]; for(int i=9;i<16;i++) mx=fmaxf(mx,s_scal[i]);
      float ex=expf(lv-mx);
      float sv=waveSum(ex);
      __syncthreads();
      if((tid&63)==0) s_scal[8+(tid>>6)]=sv;
      __syncthreads();
      float se=0; for(int i=8;i<16;i++) se+=s_scal[i]; se*=0.5f;
      if(tid<256){
        float cw=ex/se;
        float ag=sigf(s_ctrl[389]), wg=sigf(s_ctrl[390]);
        float wd=wg*(ag*s_alloc[tid]+(1.f-ag)*cw);
        s_wd[tid]=wd;
        if((tid>>4)==s) g_storef(wdist_g+b*256+tid,wd);
      }
    }
    __syncthreads();
    {
      float wv=waveSum(s_wd[tid&255]);
      if((tid&63)==0) s_scal[8+(tid>>6)]=wv;
      __syncthreads();
      float swd=0; for(int i=8;i<16;i++) swd+=s_scal[i]; swd*=0.5f;
      if(tid<16){
        int n=s*16+tid;
        float po=prec_g[b*256+n];
        s_preo[tid]=po;
        prec_g[b*256+n]=(1.f-swd)*po+s_wd[n];
      }
    }
    __syncthreads();
    {
      int nr=tid>>5, ic=tid&31;
      int n=s*16+nr;
      float wdn=s_wd[n], pre=s_preo[nr];
      float4* lp=(float4*)(linkT_g+((size_t)(b*256+n))*256);
#pragma unroll
      for(int h2=0;h2<2;h2++){
        int i4=ic*2+h2;
        float4 l=lp[i4];
        int i0=i4*4;
        float w0=s_wd[i0],w1=s_wd[i0+1],w2=s_wd[i0+2],w3=s_wd[i0+3];
        float4 nl;
        nl.x=(i0  ==n)?0.f:((1.f-w0-wdn)*l.x+w0*pre);
        nl.y=(i0+1==n)?0.f:((1.f-w1-wdn)*l.y+w1*pre);
        nl.z=(i0+2==n)?0.f:((1.f-w2-wdn)*l.z+w2*pre);
        nl.w=(i0+3==n)?0.f:((1.f-w3-wdn)*l.w+w3*pre);
        lp[i4]=nl;
        *(float4*)&s_link[nr*256+i0]=nl;
      }
    }
    __syncthreads();
    {   // bwd partials (owned n, full i)
      int nr=tid>>5, ic=tid&31;
      float b0=0,b1=0,b2=0,b3=0;
#pragma unroll
      for(int q=0;q<8;q++){
        int i=ic*8+q;
        float l=s_link[nr*256+i];
        b0+=l*s_prd[i]; b1+=l*s_prd[256+i]; b2+=l*s_prd[512+i]; b3+=l*s_prd[768+i];
      }
      s_red[(0*16+nr)*32+ic]=b0; s_red[(1*16+nr)*32+ic]=b1;
      s_red[(2*16+nr)*32+ic]=b2; s_red[(3*16+nr)*32+ic]=b3;
    }
    __syncthreads();
    if(tid<64){
      int r=tid>>4, nr=tid&15;
      float a=0;
#pragma unroll
      for(int q=0;q<32;q++) a+=s_red[(r*16+nr)*32+q];
      g_storef(bwd_g + b*1024 + r*256 + s*16+nr, a);
    }
    {   // fwd partials over owned j, all n'
      int np=tid&255, dh=tid>>8;
      float f0=0,f1=0;
#pragma unroll
      for(int jr=0;jr<16;jr++){
        float l=s_link[jr*256+np];
        int j=s*16+jr;
        f0+=l*s_prd[(2*dh)*256+j];
        f1+=l*s_prd[(2*dh+1)*256+j];
      }
      g_storef(fwdp_g + ((size_t)(b*NSB+s))*1024 + (2*dh)*256 + np, f0);
      g_storef(fwdp_g + ((size_t)(b*NSB+s))*1024 + (2*dh+1)*256 + np, f1);
    }
    {   // mem update owned rows + LDS stage
      int nr=tid>>5, wq=tid&31;
      int n=s*16+nr;
      float ps=s_psi[n], wdn=s_wd[n];
      float4* mr=(float4*)(mem_g+((size_t)(b*256+n))*WL);
      float4 m=mr[wq]; int w=wq*4;
      m.x=m.x*ps*(1.f-wdn*s_er[w  ])+wdn*s_ctrl[256+w  ];
      m.y=m.y*ps*(1.f-wdn*s_er[w+1])+wdn*s_ctrl[256+w+1];
      m.z=m.z*ps*(1.f-wdn*s_er[w+2])+wdn*s_ctrl[256+w+2];
      m.w=m.w*ps*(1.f-wdn*s_er[w+3])+wdn*s_ctrl[256+w+3];
      mr[wq]=m;
      *(float4*)&s_mem[nr*128+w]=m;
    }
    __syncthreads();
    {   // read-key dots + new mem norms from s_mem
      int nr=tid>>5, wq=tid&31;
      float4 m=*(float4*)&s_mem[nr*128+wq*4];
      int w=wq*4;
      const float* k0=s_ctrl+WCH;
      const float* k1=s_ctrl+WCH+132;
      const float* k2=s_ctrl+WCH+264;
      const float* k3=s_ctrl+WCH+396;
      float d0=m.x*k0[w]+m.y*k0[w+1]+m.z*k0[w+2]+m.w*k0[w+3];
      float d1=m.x*k1[w]+m.y*k1[w+1]+m.z*k1[w+2]+m.w*k1[w+3];
      float d2=m.x*k2[w]+m.y*k2[w+1]+m.z*k2[w+2]+m.w*k2[w+3];
      float d3=m.x*k3[w]+m.y*k3[w+1]+m.z*k3[w+2]+m.w*k3[w+3];
      float m2=m.x*m.x+m.y*m.y+m.z*m.z+m.w*m.w;
      s_red[(0*16+nr)*32+wq]=d0; s_red[(1*16+nr)*32+wq]=d1;
      s_red[(2*16+nr)*32+wq]=d2; s_red[(3*16+nr)*32+wq]=d3;
      s_red[2048+nr*32+wq]=m2;
    }
    if(tid<256){   // read-key norms
      int r=tid>>6, l=tid&63;
      const float* kk=s_ctrl+WCH+r*132;
      float kv=kk[l]*kk[l]+kk[l+64]*kk[l+64];
      kv=waveSum(kv);
      if(l==0) s_scal[4+r]=sqrtf(kv);
    }
    __syncthreads();
    if(tid<16){
      float m2=0;
#pragma unroll
      for(int q=0;q<32;q++) m2+=s_red[2048+tid*32+q];
      s_mn[tid]=sqrtf(m2);
    }
    __syncthreads();
    if(tid<64){
      int r=tid>>4, nr=tid&15;
      float dt=0;
#pragma unroll
      for(int q=0;q<32;q++) dt+=s_red[(r*16+nr)*32+q];
      float rb=oneplusf(s_ctrl[WCH+r*132+128]);
      float lg=dt*rb/(s_scal[4+r]*s_mn[nr]+EPSF);
      g_storef(rlog_g+b*1024+r*256+s*16+nr,lg);
    }
    batbar(cnt,flg,++bcnt);

    // ============ PHASE E: fwd reduce, sharpen, read softmax, r_dist, rdata ============
    {
      float2 a={0,0};
#pragma unroll
      for(int p=0;p<NSB;p++){
        float2 v=g_loadf2(fwdp_g + ((size_t)(b*NSB+p))*1024 + 2*tid);
        a.x+=v.x; a.y+=v.y;
      }
      s_fwd[2*tid]=a.x; s_fwd[2*tid+1]=a.y;
    }
    {
      float2 v=g_loadf2(bwd_g+b*1024+2*tid);
      s_bwd[2*tid]=v.x; s_bwd[2*tid+1]=v.y;
    }
    {
      float2 v=g_loadf2(rlog_g+b*1024+2*tid);
      s_red[2*tid]=v.x; s_red[2*tid+1]=v.y;
    }
    __syncthreads();
    {   // sharpen: wave w -> row (0-3 fwd, 4-7 bwd)
      int l=tid&63, w=tid>>6;
      float* rp=(w<4)? (s_fwd+w*256) : (s_bwd+(w-4)*256);
      float a=rp[l]+EPSF, b2=rp[l+64]+EPSF, c2=rp[l+128]+EPSF, d2=rp[l+192]+EPSF;
      float mxr=waveMax(fmaxf(fmaxf(a,b2),fmaxf(c2,d2)));
      mxr=__shfl(mxr,0,64);
      float ff=oneplusf(s_ctrl[919+w]);
      a=powf(a/mxr,ff); b2=powf(b2/mxr,ff); c2=powf(c2/mxr,ff); d2=powf(d2/mxr,ff);
      float sm=waveSum(a+b2+c2+d2);
      sm=__shfl(sm,0,64);
      float inv=1.f/sm;
      rp[l]=a*inv; rp[l+64]=b2*inv; rp[l+128]=c2*inv; rp[l+192]=d2*inv;
    }
    {   // read softmax on s_red rows (dup waves write identical values)
      int l=tid&63, w=tid>>6, row=w&3;
      float* rr=s_red+row*256;
      float a=rr[l],b2=rr[l+64],c2=rr[l+128],d2=rr[l+192];
      float mx2=waveMax(fmaxf(fmaxf(a,b2),fmaxf(c2,d2)));
      mx2=__shfl(mx2,0,64);
      a=expf(a-mx2); b2=expf(b2-mx2); c2=expf(c2-mx2); d2=expf(d2-mx2);
      float sm=waveSum(a+b2+c2+d2);
      sm=__shfl(sm,0,64);
      float inv=1.f/sm;
      rr[l]=a*inv; rr[l+64]=b2*inv; rr[l+128]=c2*inv; rr[l+192]=d2*inv;
    }
    __syncthreads();
    if(tid<256){
      int n=tid;
#pragma unroll
      for(int r=0;r<NR;r++){
        float cr=s_red[r*256+n];
        float fw=s_fwd[r*256+n];
        float bw=s_bwd[r*256+n];
        int mo=WCH+r*132+129;
        float m0=s_ctrl[mo],m1=s_ctrl[mo+1],m2s=s_ctrl[mo+2];
        float mm=fmaxf(m0,fmaxf(m1,m2s));
        float e0=expf(m0-mm),e1=expf(m1-mm),e2=expf(m2s-mm);
        float es=e0+e1+e2;
        float rdv=(e0*bw+e1*cr+e2*fw)/es;
        s_prd[r*256+n]=rdv;
        if((n>>4)==s) g_storef(rdist_g+b*1024+r*256+n,rdv);
      }
    }
    __syncthreads();
    {   // rdata partials over owned rows
      int w=tid&127, nq=tid>>7;
      float a0=0,a1=0,a2=0,a3=0;
#pragma unroll
      for(int q=0;q<4;q++){
        int nr=nq*4+q; int n=s*16+nr;
        float mv=s_mem[nr*128+w];
        a0+=s_prd[n]*mv; a1+=s_prd[256+n]*mv; a2+=s_prd[512+n]*mv; a3+=s_prd[768+n]*mv;
      }
      s_red[(0*4+nq)*128+w]=a0; s_red[(1*4+nq)*128+w]=a1;
      s_red[(2*4+nq)*128+w]=a2; s_red[(3*4+nq)*128+w]=a3;
    }
    __syncthreads();
    {
      int r=tid>>7, w=tid&127;
      float rd=s_red[(r*4+0)*128+w]+s_red[(r*4+1)*128+w]+s_red[(r*4+2)*128+w]+s_red[(r*4+3)*128+w];
      g_storef(rdp_g + ((size_t)(b*NSB+s))*512 + r*128 + w, rd);
    }
    batbar(cnt,flg,++bcnt);
  }
}

extern "C" void kernel_launch(void* const* d_in, const int* in_sizes, int n_in,
                              void* d_out, int out_size, void* d_ws, size_t ws_size,
                              hipStream_t stream) {
  const float* in_data = (const float*)d_in[0];
  const float* Wx      = (const float*)d_in[1];
  const float* Wh      = (const float*)d_in[2];
  const float* b_lstm  = (const float*)d_in[3];
  const float* Wc      = (const float*)d_in[4];
  const float* bc      = (const float*)d_in[5];
  const float* Wo      = (const float*)d_in[6];
  const float* bo      = (const float*)d_in[7];
  const float* Wr      = (const float*)d_in[8];
  const float* br      = (const float*)d_in[9];
  float* out = (float*)d_out;
  float* ws  = (float*)d_ws;

  size_t off=0;
  float* mem_    = ws+off; off += (size_t)NB*NC*WL;        // 524288
  float* linkT_  = ws+off; off += (size_t)NB*NC*NC;        // 1048576
  float* usages_ = ws+off; off += 2*NB*NC;                 // ping-pong (race fix)
  float* prec_   = ws+off; off += NB*NC;
  float* wdist_  = ws+off; off += NB*NC;
  float* rdist_  = ws+off; off += NB*NR*NC;                // 16384
  float* rdp_    = ws+off; off += (size_t)NB*NSB*NR*WL;    // 131072
  float* h_      = ws+off; off += 2*NB*HIDN;               // ping-pong (race fix)
  float* c_      = ws+off; off += NB*HIDN;
  float* ctrl_   = ws+off; off += NB*928;
  float* dots_   = ws+off; off += NB*NC;
  float* bwd_    = ws+off; off += NB*NR*NC;
  float* fwdp_   = ws+off; off += (size_t)NB*NSB*NR*NC;    // 262144
  float* rlog_   = ws+off; off += NB*NR*NC;
  int*   bar_    = (int*)(ws+off); off += 512;             // 16 batches x 32 ints
  size_t zero_floats = off;                                // ~2.07M floats
  float* xpart_  = ws+off; off += (size_t)NT*NB*G4;        // 2097152
  // total ~4.17M floats = 16.7 MB (< R2's proven 17.2 MB)

  k_zero<<<256,256,0,stream>>>(ws, zero_floats);
  k_xpart<<<1024,256,0,stream>>>(in_data, Wx, xpart_);

  k_persist<<<NBLK,THR,0,stream>>>(Wx,Wh,b_lstm,Wc,bc,Wo,bo,Wr,br,
                                   xpart_,mem_,linkT_,usages_,prec_,
                                   wdist_,rdist_,rdp_,h_,c_,
                                   ctrl_,dots_,bwd_,fwdp_,rlog_,out,bar_);
}

// Round 9
// 5113.531 us; speedup vs baseline: 3.0560x; 1.1441x over previous
//
#include <hip/hip_runtime.h>
#include <math.h>

#define NT   64
#define NB   16
#define OUTS 256
#define WL   128
#define NC   256
#define NR   4
#define HIDN 512
#define G4   2048
#define WCH  391
#define COUT 927
#define EPSF 1e-6f
#define NBLK 256
#define THR  512
#define NSB  16    // blocks per batch
#define SLC  16    // cells owned per block

__device__ __forceinline__ float sigf(float x){ return 1.0f/(1.0f+expf(-x)); }
__device__ __forceinline__ float oneplusf(float x){ return fmaxf(x,0.0f)+log1pf(expf(-fabsf(x)))+1.0f; }

__device__ __forceinline__ float waveSum(float v){
#pragma unroll
  for(int o=32;o>0;o>>=1) v += __shfl_down(v,o,64);
  return v;
}
__device__ __forceinline__ float waveMax(float v){
#pragma unroll
  for(int o=32;o>0;o>>=1) v = fmaxf(v,__shfl_down(v,o,64));
  return v;
}

// relaxed agent-scope (LLC-coherent) accessors for cross-block tensors
__device__ __forceinline__ void g_storef(float* p, float v){
  __hip_atomic_store(p, v, __ATOMIC_RELAXED, __HIP_MEMORY_SCOPE_AGENT);
}
__device__ __forceinline__ float g_loadf(const float* p){
  return __hip_atomic_load((float*)p, __ATOMIC_RELAXED, __HIP_MEMORY_SCOPE_AGENT);
}
__device__ __forceinline__ float2 g_loadf2(const float* p){
  unsigned long long v = __hip_atomic_load((const unsigned long long*)p, __ATOMIC_RELAXED, __HIP_MEMORY_SCOPE_AGENT);
  union{unsigned long long u; float2 f;} c; c.u=v; return c.f;
}

// per-batch barrier (16 blocks), fence-free protocol validated R3/R5/R8
__device__ __forceinline__ void batbar(int* cnt, int* flg, int phase){
  __syncthreads();
  if (threadIdx.x == 0){
    asm volatile("s_waitcnt vmcnt(0) lgkmcnt(0)" ::: "memory");
    int prev = __hip_atomic_fetch_add(cnt, 1, __ATOMIC_RELAXED, __HIP_MEMORY_SCOPE_AGENT);
    if (prev == NSB*phase - 1){
      __hip_atomic_store(flg, phase, __ATOMIC_RELAXED, __HIP_MEMORY_SCOPE_AGENT);
    } else {
      while (__hip_atomic_load(flg, __ATOMIC_RELAXED, __HIP_MEMORY_SCOPE_AGENT) < phase)
        __builtin_amdgcn_s_sleep(1);
    }
    asm volatile("" ::: "memory");
  }
  __syncthreads();
}

__global__ void k_zero(float* p, size_t n){
  size_t i = (size_t)blockIdx.x*blockDim.x + threadIdx.x;
  size_t st = (size_t)gridDim.x*blockDim.x;
  for(; i<n; i+=st) p[i]=0.0f;
}

// xpart[(t*NB+bi)][2048] = x_t @ Wx[0:256,:]  (hoisted, fully parallel)
__global__ __launch_bounds__(256) void k_xpart(
    const float* __restrict__ in_data, const float* __restrict__ Wx, float* __restrict__ xpart)
{
  int jb = blockIdx.x & 15, rt = blockIdx.x >> 4;
  int jg = threadIdx.x & 15, rl = threadIdx.x >> 4;
  int row = rt*16 + rl;
  int j0 = jb*128 + jg*8;
  const float* x = in_data + (size_t)row*256;
  float acc[8];
#pragma unroll
  for(int i=0;i<8;i++) acc[i]=0.0f;
  for(int k=0;k<256;k++){
    float a = x[k];
    const float* w = Wx + (size_t)k*G4 + j0;
    float4 w0 = *(const float4*)w, w1 = *(const float4*)(w+4);
    acc[0]+=a*w0.x; acc[1]+=a*w0.y; acc[2]+=a*w0.z; acc[3]+=a*w0.w;
    acc[4]+=a*w1.x; acc[5]+=a*w1.y; acc[6]+=a*w1.z; acc[7]+=a*w1.w;
  }
  float* xp = xpart + (size_t)row*G4 + j0;
#pragma unroll
  for(int i=0;i<8;i++) xp[i]=acc[i];
}

__global__ __launch_bounds__(THR,1) void k_persist(
    const float* __restrict__ Wx, const float* __restrict__ Wh, const float* __restrict__ b_lstm,
    const float* __restrict__ Wc, const float* __restrict__ bc,
    const float* __restrict__ Wo, const float* __restrict__ bo,
    const float* __restrict__ Wr, const float* __restrict__ br,
    const float* __restrict__ xpart,
    float* mem_g, float* linkT_g, float* usages_g, float* prec_g,
    float* wdist_g, float* rdist_g, float* racc_g, float* h_g, float* c_g,
    float* ctrl_g, float* dots_g, float* bwd_g, float* facc_g, float* rlog_g,
    float* out_g, int* bar)
{
  __shared__ float s_act[1024];
  __shared__ float s_ctrl[928];
  __shared__ float s_prd[1024];
  __shared__ float s_psi[256], s_u2[256], s_alloc[256], s_wd[256];
  __shared__ float s_er[128];
  __shared__ float s_preo[16], s_mn[16];
  __shared__ float s_scal[32], s_sct[16];
  __shared__ float s_rk[256], s_su[256], s_shift[256];
  __shared__ float s_link[SLC*256];   // owned linkT rows (new)
  __shared__ float s_mem[SLC*128];    // owned mem rows (new)
  __shared__ float s_red[2560];
  __shared__ float s_fwd[1024], s_bwd[1024];

  const int tid = threadIdx.x, blk = blockIdx.x;
  const int s = blk & 15, b = blk >> 4;
  int* cnt = bar + b*32;
  int* flg = bar + b*32 + 16;
  int bcnt = 0;

  for(int t=0;t<=NT;t++){
    // double-buffer parity: read old (t&1), write new ((t+1)&1)
    const float* h_old = h_g + (t&1)*(NB*HIDN);
    float*       h_new = h_g + ((t+1)&1)*(NB*HIDN);
    const float* u_old = usages_g + (t&1)*(NB*NC);
    float*       u_new = usages_g + ((t+1)&1)*(NB*NC);

    // ============ PHASE A: stage act, gates GEMM, LSTM, out(t-1), zero facc ============
    if(tid<256){
      float2 v = g_loadf2(racc_g + b*512 + 2*tid);   // rdata(t-1), pre-reduced
      s_act[2*tid]=v.x; s_act[2*tid+1]=v.y;
    } else {
      int i=tid-256;
      float2 v = g_loadf2(h_old + b*HIDN + 2*i);
      s_act[512+2*i]=v.x; s_act[512+2*i+1]=v.y;
    }
    if(tid<64) g_storef(facc_g + b*1024 + s*64 + tid, 0.0f);   // zero owned fwd-acc slice
    __syncthreads();
    if(t<NT){
      // thread = (q4: gate g=q4>>3, quad jq=q4&7) x (ks: 16 k-splits of 64); float4 weight loads
      int q4=tid&31, ks=tid>>5;
      int g=q4>>3, jq=q4&7;
      int cbase = g*512 + s*32 + jq*4;
      float4 acc={0,0,0,0};
      for(int kk=0;kk<64;kk++){
        int k=ks*64+kk;
        float av=s_act[k];
        const float* wr = (k<512) ? (Wx + (size_t)(256+k)*G4) : (Wh + (size_t)(k-512)*G4);
        float4 w4 = *(const float4*)(wr + cbase);
        acc.x+=av*w4.x; acc.y+=av*w4.y; acc.z+=av*w4.z; acc.w+=av*w4.w;
      }
      int c0 = g*32 + jq*4;                 // layout [ks][c]: conflict-light
      s_red[ks*128+c0  ]=acc.x;
      s_red[ks*128+c0+1]=acc.y;
      s_red[ks*128+c0+2]=acc.z;
      s_red[ks*128+c0+3]=acc.w;
    }
    if(t>0){
      int jl=tid&15, ks2=tid>>4;           // 16 j x 32 ksplit(32)
      int j=s*16+jl;
      float acc=0;
      for(int kk=0;kk<32;kk++){
        int k=ks2*32+kk;
        float av=s_act[k];
        const float* wr=(k<512)?(Wr+(size_t)k*OUTS):(Wo+(size_t)(k-512)*OUTS);
        acc += av*wr[j];
      }
      s_red[2048 + ks2*16 + jl]=acc;       // [ks2][jl]: conflict-free
    }
    __syncthreads();
    if(t<NT && tid<32){
      int jj=tid;
      float g[4];
#pragma unroll
      for(int gg=0;gg<4;gg++){
        float v=0;
#pragma unroll
        for(int q=0;q<16;q++) v+=s_red[q*128 + gg*32 + jj];
        int col=gg*512+s*32+jj;
        v += xpart[((size_t)t*NB+b)*G4 + col] + b_lstm[col];
        g[gg]=v;
      }
      int ci = b*HIDN + s*32+jj;
      float c = sigf(g[1])*c_g[ci] + sigf(g[0])*tanhf(g[2]);
      float h = sigf(g[3])*tanhf(c);
      c_g[ci]=c;
      g_storef(h_new+ci, h);
    }
    if(t>0 && tid>=64 && tid<80){
      int jl=tid-64; int j=s*16+jl;
      float acc=bo[j]+br[j];
#pragma unroll
      for(int q=0;q<32;q++) acc+=s_red[2048 + q*16 + jl];
      out_g[((size_t)(t-1)*NB+b)*OUTS + j]=acc;
    }
    if(t==NT) break;
    batbar(cnt,flg,++bcnt);

    // ============ PHASE B: ctrl = clip(h @ Wc + bc); zero racc ============
    if(tid<256){
      float2 v = g_loadf2(h_new + b*HIDN + 2*tid);
      s_act[2*tid]=v.x; s_act[2*tid+1]=v.y;
    }
    if(tid>=256 && tid<288) g_storef(racc_g + b*512 + s*32 + (tid-256), 0.0f);
    __syncthreads();
    {
      int cl=tid&63, ks=tid>>6;            // 64 col-slots x 8 ksplit(64)
      int j=s*58+cl;
      float acc=0;
      if(cl<58 && j<COUT){
        for(int kk=0;kk<64;kk++){
          int k=ks*64+kk;
          acc += s_act[k]*Wc[(size_t)k*COUT + j];
        }
      }
      s_red[ks*64+cl]=acc;                 // [ks][cl]: conflict-free
    }
    __syncthreads();
    if(tid<58){
      int j=s*58+tid;
      if(j<COUT){
        float a=bc[j];
#pragma unroll
        for(int q=0;q<8;q++) a+=s_red[q*64+tid];
        g_storef(ctrl_g + b*928 + j, fminf(fmaxf(a,-20.f),20.f));
      }
    }
    batbar(cnt,flg,++bcnt);

    // ============ PHASE C: psi/usage/alloc + write-key dots ============
    if(tid<464){
      float2 v = g_loadf2(ctrl_g + b*928 + 2*tid);
      s_ctrl[2*tid]=v.x; s_ctrl[2*tid+1]=v.y;
    }
    {
      float2 v = g_loadf2(rdist_g + b*1024 + 2*tid);
      s_prd[2*tid]=v.x; s_prd[2*tid+1]=v.y;
    }
    __syncthreads();
    if(tid<256){
      int n=tid;
      float psi=1.f;
#pragma unroll
      for(int r=0;r<NR;r++) psi *= 1.f - sigf(s_ctrl[384+r])*s_prd[r*256+n];
      s_psi[n]=psi;
      float uo=g_loadf(u_old+b*256+n), pw=g_loadf(wdist_g+b*256+n);
      float u=(uo+pw-uo*pw)*psi;
      if((n>>4)==s) g_storef(u_new+b*256+n,u);
      s_u2[n]=u*(1.f-EPSF)+EPSF;
    } else if(tid<384){
      int w=tid-256; s_er[w]=sigf(s_ctrl[128+w]);
    } else if(tid>=448){
      int l=tid-448;
      float v=s_ctrl[l]*s_ctrl[l]+s_ctrl[l+64]*s_ctrl[l+64];
      v=waveSum(v);
      if(l==0) s_scal[0]=v;
    }
    __syncthreads();
    {
      int n=tid&255, hf=tid>>8;
      float u2=s_u2[n]; int c=0;
      for(int jj=0;jj<128;jj++){
        int j=hf*128+jj; float uj=s_u2[j];
        c += (uj<u2)||(uj==u2 && j<n);
      }
      s_red[hf*256+n]=(float)c;
    }
    __syncthreads();
    if(tid<256){
      int rk=(int)(s_red[tid]+s_red[256+tid]);
      s_rk[tid]=(float)rk;
      s_su[rk]=s_u2[tid];
    }
    __syncthreads();
    if(tid<16){
      float run=1.f;
#pragma unroll
      for(int i=0;i<16;i++){ int idx=tid*16+i; s_shift[idx]=run; run*=s_su[idx]; }
      s_sct[tid]=run;
    }
    __syncthreads();
    if(tid==0){
      float run=1.f;
      for(int j=0;j<16;j++){ float t2=s_sct[j]; s_sct[j]=run; run*=t2; }
    }
    __syncthreads();
    if(tid<256){
      int rk=(int)s_rk[tid];
      s_alloc[tid]=(1.f-s_u2[tid])*s_shift[rk]*s_sct[rk>>4];
    }
    {
      int nr=tid>>5, wq=tid&31;            // 16 owned rows x 32 float4
      int n=s*16+nr;
      float4 m=((const float4*)(mem_g + ((size_t)(b*256+n))*WL))[wq];
      int w=wq*4;
      float dt=m.x*s_ctrl[w]+m.y*s_ctrl[w+1]+m.z*s_ctrl[w+2]+m.w*s_ctrl[w+3];
      float m2=m.x*m.x+m.y*m.y+m.z*m.z+m.w*m.w;
      s_red[nr*32+wq]=dt; s_red[512+nr*32+wq]=m2;
    }
    __syncthreads();
    if(tid<16){
      float dt=0,m2=0;
#pragma unroll
      for(int q=0;q<32;q++){ dt+=s_red[tid*32+q]; m2+=s_red[512+tid*32+q]; }
      float wb=oneplusf(s_ctrl[388]);
      float lg=dt*wb/(sqrtf(s_scal[0])*sqrtf(m2)+EPSF);
      g_storef(dots_g+b*256+s*16+tid, lg);
    }
    batbar(cnt,flg,++bcnt);

    // ============ PHASE D: write softmax, link, fwd/bwd, mem, read dots ============
    if(tid<128){
      float2 v=g_loadf2(dots_g+b*256+2*tid);
      s_red[2*tid]=v.x; s_red[2*tid+1]=v.y;
    }
    __syncthreads();
    {
      float lv=s_red[tid&255];
      float mv=waveMax(lv);
      if((tid&63)==0) s_scal[8+(tid>>6)]=mv;
      __syncthreads();
      float mx=s_scal[8]; for(int i=9;i<16;i++) mx=fmaxf(mx,s_scal[i]);
      float ex=expf(lv-mx);
      float sv=waveSum(ex);
      __syncthreads();
      if((tid&63)==0) s_scal[8+(tid>>6)]=sv;
      __syncthreads();
      float se=0; for(int i=8;i<16;i++) se+=s_scal[i]; se*=0.5f;
      if(tid<256){
        float cw=ex/se;
        float ag=sigf(s_ctrl[389]), wg=sigf(s_ctrl[390]);
        float wd=wg*(ag*s_alloc[tid]+(1.f-ag)*cw);
        s_wd[tid]=wd;
        if((tid>>4)==s) g_storef(wdist_g+b*256+tid,wd);
      }
    }
    __syncthreads();
    {
      float wv=waveSum(s_wd[tid&255]);
      if((tid&63)==0) s_scal[8+(tid>>6)]=wv;
      __syncthreads();
      float swd=0; for(int i=8;i<16;i++) swd+=s_scal[i]; swd*=0.5f;
      if(tid<16){
        int n=s*16+tid;
        float po=prec_g[b*256+n];
        s_preo[tid]=po;
        prec_g[b*256+n]=(1.f-swd)*po+s_wd[n];
      }
    }
    __syncthreads();
    {
      int nr=tid>>5, ic=tid&31;
      int n=s*16+nr;
      float wdn=s_wd[n], pre=s_preo[nr];
      float4* lp=(float4*)(linkT_g+((size_t)(b*256+n))*256);
#pragma unroll
      for(int h2=0;h2<2;h2++){
        int i4=ic*2+h2;
        float4 l=lp[i4];
        int i0=i4*4;
        float w0=s_wd[i0],w1=s_wd[i0+1],w2=s_wd[i0+2],w3=s_wd[i0+3];
        float4 nl;
        nl.x=(i0  ==n)?0.f:((1.f-w0-wdn)*l.x+w0*pre);
        nl.y=(i0+1==n)?0.f:((1.f-w1-wdn)*l.y+w1*pre);
        nl.z=(i0+2==n)?0.f:((1.f-w2-wdn)*l.z+w2*pre);
        nl.w=(i0+3==n)?0.f:((1.f-w3-wdn)*l.w+w3*pre);
        lp[i4]=nl;
        *(float4*)&s_link[nr*256+i0]=nl;
      }
    }
    __syncthreads();
    {   // bwd partials (owned n, full i)
      int nr=tid>>5, ic=tid&31;
      float b0=0,b1=0,b2=0,b3=0;
#pragma unroll
      for(int q=0;q<8;q++){
        int i=ic*8+q;
        float l=s_link[nr*256+i];
        b0+=l*s_prd[i]; b1+=l*s_prd[256+i]; b2+=l*s_prd[512+i]; b3+=l*s_prd[768+i];
      }
      s_red[(0*16+nr)*32+ic]=b0; s_red[(1*16+nr)*32+ic]=b1;
      s_red[(2*16+nr)*32+ic]=b2; s_red[(3*16+nr)*32+ic]=b3;
    }
    __syncthreads();
    if(tid<64){
      int r=tid>>4, nr=tid&15;
      float a=0;
#pragma unroll
      for(int q=0;q<32;q++) a+=s_red[(r*16+nr)*32+q];
      g_storef(bwd_g + b*1024 + r*256 + s*16+nr, a);
    }
    {   // fwd contributions from owned n-slice to all i: atomicAdd (facc zeroed in phase A)
      int np=tid&255, dh=tid>>8;
      float f0=0,f1=0;
#pragma unroll
      for(int jr=0;jr<16;jr++){
        float l=s_link[jr*256+np];
        int j=s*16+jr;
        f0+=l*s_prd[(2*dh)*256+j];
        f1+=l*s_prd[(2*dh+1)*256+j];
      }
      atomicAdd(facc_g + b*1024 + (2*dh)*256 + np, f0);
      atomicAdd(facc_g + b*1024 + (2*dh+1)*256 + np, f1);
    }
    {   // mem update owned rows + LDS stage
      int nr=tid>>5, wq=tid&31;
      int n=s*16+nr;
      float ps=s_psi[n], wdn=s_wd[n];
      float4* mr=(float4*)(mem_g+((size_t)(b*256+n))*WL);
      float4 m=mr[wq]; int w=wq*4;
      m.x=m.x*ps*(1.f-wdn*s_er[w  ])+wdn*s_ctrl[256+w  ];
      m.y=m.y*ps*(1.f-wdn*s_er[w+1])+wdn*s_ctrl[256+w+1];
      m.z=m.z*ps*(1.f-wdn*s_er[w+2])+wdn*s_ctrl[256+w+2];
      m.w=m.w*ps*(1.f-wdn*s_er[w+3])+wdn*s_ctrl[256+w+3];
      mr[wq]=m;
      *(float4*)&s_mem[nr*128+w]=m;
    }
    __syncthreads();
    {   // read-key dots + new mem norms from s_mem
      int nr=tid>>5, wq=tid&31;
      float4 m=*(float4*)&s_mem[nr*128+wq*4];
      int w=wq*4;
      const float* k0=s_ctrl+WCH;
      const float* k1=s_ctrl+WCH+132;
      const float* k2=s_ctrl+WCH+264;
      const float* k3=s_ctrl+WCH+396;
      float d0=m.x*k0[w]+m.y*k0[w+1]+m.z*k0[w+2]+m.w*k0[w+3];
      float d1=m.x*k1[w]+m.y*k1[w+1]+m.z*k1[w+2]+m.w*k1[w+3];
      float d2=m.x*k2[w]+m.y*k2[w+1]+m.z*k2[w+2]+m.w*k2[w+3];
      float d3=m.x*k3[w]+m.y*k3[w+1]+m.z*k3[w+2]+m.w*k3[w+3];
      float m2=m.x*m.x+m.y*m.y+m.z*m.z+m.w*m.w;
      s_red[(0*16+nr)*32+wq]=d0; s_red[(1*16+nr)*32+wq]=d1;
      s_red[(2*16+nr)*32+wq]=d2; s_red[(3*16+nr)*32+wq]=d3;
      s_red[2048+nr*32+wq]=m2;
    }
    if(tid<256){   // read-key norms
      int r=tid>>6, l=tid&63;
      const float* kk=s_ctrl+WCH+r*132;
      float kv=kk[l]*kk[l]+kk[l+64]*kk[l+64];
      kv=waveSum(kv);
      if(l==0) s_scal[4+r]=sqrtf(kv);
    }
    __syncthreads();
    if(tid<16){
      float m2=0;
#pragma unroll
      for(int q=0;q<32;q++) m2+=s_red[2048+tid*32+q];
      s_mn[tid]=sqrtf(m2);
    }
    __syncthreads();
    if(tid<64){
      int r=tid>>4, nr=tid&15;
      float dt=0;
#pragma unroll
      for(int q=0;q<32;q++) dt+=s_red[(r*16+nr)*32+q];
      float rb=oneplusf(s_ctrl[WCH+r*132+128]);
      float lg=dt*rb/(s_scal[4+r]*s_mn[nr]+EPSF);
      g_storef(rlog_g+b*1024+r*256+s*16+nr,lg);
    }
    batbar(cnt,flg,++bcnt);

    // ============ PHASE E: read fwd/bwd/rlog, sharpen, read softmax, r_dist, rdata ============
    {
      float2 v=g_loadf2(facc_g + b*1024 + 2*tid);
      s_fwd[2*tid]=v.x; s_fwd[2*tid+1]=v.y;
    }
    {
      float2 v=g_loadf2(bwd_g+b*1024+2*tid);
      s_bwd[2*tid]=v.x; s_bwd[2*tid+1]=v.y;
    }
    {
      float2 v=g_loadf2(rlog_g+b*1024+2*tid);
      s_red[2*tid]=v.x; s_red[2*tid+1]=v.y;
    }
    __syncthreads();
    {   // sharpen: wave w -> row (0-3 fwd, 4-7 bwd)
      int l=tid&63, w=tid>>6;
      float* rp=(w<4)? (s_fwd+w*256) : (s_bwd+(w-4)*256);
      float a=rp[l]+EPSF, b2=rp[l+64]+EPSF, c2=rp[l+128]+EPSF, d2=rp[l+192]+EPSF;
      float mxr=waveMax(fmaxf(fmaxf(a,b2),fmaxf(c2,d2)));
      mxr=__shfl(mxr,0,64);
      float ff=oneplusf(s_ctrl[919+w]);
      a=powf(a/mxr,ff); b2=powf(b2/mxr,ff); c2=powf(c2/mxr,ff); d2=powf(d2/mxr,ff);
      float sm=waveSum(a+b2+c2+d2);
      sm=__shfl(sm,0,64);
      float inv=1.f/sm;
      rp[l]=a*inv; rp[l+64]=b2*inv; rp[l+128]=c2*inv; rp[l+192]=d2*inv;
    }
    {   // read softmax on s_red rows (dup waves write identical values)
      int l=tid&63, w=tid>>6, row=w&3;
      float* rr=s_red+row*256;
      float a=rr[l],b2=rr[l+64],c2=rr[l+128],d2=rr[l+192];
      float mx2=waveMax(fmaxf(fmaxf(a,b2),fmaxf(c2,d2)));
      mx2=__shfl(mx2,0,64);
      a=expf(a-mx2); b2=expf(b2-mx2); c2=expf(c2-mx2); d2=expf(d2-mx2);
      float sm=waveSum(a+b2+c2+d2);
      sm=__shfl(sm,0,64);
      float inv=1.f/sm;
      rr[l]=a*inv; rr[l+64]=b2*inv; rr[l+128]=c2*inv; rr[l+192]=d2*inv;
    }
    __syncthreads();
    if(tid<256){
      int n=tid;
#pragma unroll
      for(int r=0;r<NR;r++){
        float cr=s_red[r*256+n];
        float fw=s_fwd[r*256+n];
        float bw=s_bwd[r*256+n];
        int mo=WCH+r*132+129;
        float m0=s_ctrl[mo],m1=s_ctrl[mo+1],m2s=s_ctrl[mo+2];
        float mm=fmaxf(m0,fmaxf(m1,m2s));
        float e0=expf(m0-mm),e1=expf(m1-mm),e2=expf(m2s-mm);
        float es=e0+e1+e2;
        float rdv=(e0*bw+e1*cr+e2*fw)/es;
        s_prd[r*256+n]=rdv;
        if((n>>4)==s) g_storef(rdist_g+b*1024+r*256+n,rdv);
      }
    }
    __syncthreads();
    {   // rdata partials over owned rows
      int w=tid&127, nq=tid>>7;
      float a0=0,a1=0,a2=0,a3=0;
#pragma unroll
      for(int q=0;q<4;q++){
        int nr=nq*4+q; int n=s*16+nr;
        float mv=s_mem[nr*128+w];
        a0+=s_prd[n]*mv; a1+=s_prd[256+n]*mv; a2+=s_prd[512+n]*mv; a3+=s_prd[768+n]*mv;
      }
      s_red[(0*4+nq)*128+w]=a0; s_red[(1*4+nq)*128+w]=a1;
      s_red[(2*4+nq)*128+w]=a2; s_red[(3*4+nq)*128+w]=a3;
    }
    __syncthreads();
    {
      int r=tid>>7, w=tid&127;
      float rd=s_red[(r*4+0)*128+w]+s_red[(r*4+1)*128+w]+s_red[(r*4+2)*128+w]+s_red[(r*4+3)*128+w];
      atomicAdd(racc_g + b*512 + r*128 + w, rd);   // accumulated; read in next phase A
    }
    batbar(cnt,flg,++bcnt);
  }
}

extern "C" void kernel_launch(void* const* d_in, const int* in_sizes, int n_in,
                              void* d_out, int out_size, void* d_ws, size_t ws_size,
                              hipStream_t stream) {
  const float* in_data = (const float*)d_in[0];
  const float* Wx      = (const float*)d_in[1];
  const float* Wh      = (const float*)d_in[2];
  const float* b_lstm  = (const float*)d_in[3];
  const float* Wc      = (const float*)d_in[4];
  const float* bc      = (const float*)d_in[5];
  const float* Wo      = (const float*)d_in[6];
  const float* bo      = (const float*)d_in[7];
  const float* Wr      = (const float*)d_in[8];
  const float* br      = (const float*)d_in[9];
  float* out = (float*)d_out;
  float* ws  = (float*)d_ws;

  size_t off=0;
  float* mem_    = ws+off; off += (size_t)NB*NC*WL;        // 524288
  float* linkT_  = ws+off; off += (size_t)NB*NC*NC;        // 1048576
  float* usages_ = ws+off; off += 2*NB*NC;                 // ping-pong
  float* prec_   = ws+off; off += NB*NC;
  float* wdist_  = ws+off; off += NB*NC;
  float* rdist_  = ws+off; off += NB*NR*NC;                // 16384
  float* racc_   = ws+off; off += NB*512;                  // rdata atomic accumulator
  float* h_      = ws+off; off += 2*NB*HIDN;               // ping-pong
  float* c_      = ws+off; off += NB*HIDN;
  float* ctrl_   = ws+off; off += NB*928;
  float* dots_   = ws+off; off += NB*NC;
  float* bwd_    = ws+off; off += NB*NR*NC;
  float* facc_   = ws+off; off += NB*NR*NC;                // fwd atomic accumulator
  float* rlog_   = ws+off; off += NB*NR*NC;
  int*   bar_    = (int*)(ws+off); off += 512;             // 16 batches x 32 ints
  size_t zero_floats = off;                                // ~1.72M floats
  float* xpart_  = ws+off; off += (size_t)NT*NB*G4;        // 2097152
  // total ~3.82M floats = 15.3 MB

  k_zero<<<256,256,0,stream>>>(ws, zero_floats);
  k_xpart<<<1024,256,0,stream>>>(in_data, Wx, xpart_);

  k_persist<<<NBLK,THR,0,stream>>>(Wx,Wh,b_lstm,Wc,bc,Wo,bo,Wr,br,
                                   xpart_,mem_,linkT_,usages_,prec_,
                                   wdist_,rdist_,racc_,h_,c_,
                                   ctrl_,dots_,bwd_,facc_,rlog_,out,bar_);
}